// Round 1
// baseline (105.095 us; speedup 1.0000x reference)
//
#include <hip/hip_runtime.h>
#include <math.h>

#define BSZ 4
#define NN  256
#define CC  96

#define XIN_OFF  0
#define EH_OFF   2048          // BSZ*NN*2
#define COV_OFF  100352        // 2048 + BSZ*NN*CC

#define INV_SQRT_2PI 0.3989422804014327f
#define INV_SQRT2    0.7071067811865476f

// Phi(u) = 0.5*(1+erf(u/sqrt2)) via Abramowitz-Stegun 7.1.26, reusing
// e = exp(-u*u/2) (already computed for the Gaussian pdf). |err| <= 1.5e-7.
__device__ __forceinline__ float phi_cdf_from_exp(float u, float e) {
    const float pA = 0.3275911f;
    const float a1 = 0.254829592f, a2 = -0.284496736f, a3 = 1.421413741f,
                a4 = -1.453152027f, a5 = 1.061405429f;
    float x = fabsf(u) * INV_SQRT2;
    float t = __builtin_amdgcn_rcpf(__builtin_fmaf(pA, x, 1.0f));
    float poly = __builtin_fmaf(__builtin_fmaf(__builtin_fmaf(__builtin_fmaf(
                     a5, t, a4), t, a3), t, a2), t, a1) * t;
    float hp = 0.5f * poly * e;          // = Phi(-|u|)
    return (u >= 0.0f) ? 1.0f - hp : hp;
}

// One block per (b,i) row: Eh row, dvals -> diagonal of covar, xin copy.
__global__ __launch_bounds__(128) void relu_cov_row(
    const float* __restrict__ xin, const float* __restrict__ meanin,
    const float* __restrict__ kin, float* __restrict__ out)
{
    const int row = blockIdx.x;          // b*NN + i
    const int b   = row >> 8;
    const int i   = row & (NN - 1);
    const int tid = threadIdx.x;

    const float kd   = kin[((size_t)b * NN + i) * NN + i] + 1e-6f;
    const float var  = fmaxf(kd, 1e-8f);
    const float stdv = sqrtf(var);
    const float rstd = __builtin_amdgcn_rcpf(stdv);

    float dterm = 0.0f;
    if (tid < CC) {
        float m  = meanin[(size_t)row * CC + tid];
        float z  = m * rstd;
        float e  = __expf(-0.5f * z * z);
        float ph = INV_SQRT_2PI * e;         // phi(z)
        float Ph = phi_cdf_from_exp(z, e);   // Phi(z)
        float Eh = m * Ph + stdv * ph;
        out[EH_OFF + (size_t)row * CC + tid] = Eh;
        dterm = (m * m + stdv * stdv) * Ph + m * stdv * ph - Eh * Eh;
    } else if (tid < CC + 2) {
        int dd = tid - CC;                   // xin copy (d=2)
        out[XIN_OFF + (size_t)row * 2 + dd] = xin[(size_t)row * 2 + dd];
    }

    // reduce dterm across the 128-thread block (only first 96 nonzero)
    float v = dterm;
    v += __shfl_down(v, 32, 64);
    v += __shfl_down(v, 16, 64);
    v += __shfl_down(v,  8, 64);
    v += __shfl_down(v,  4, 64);
    v += __shfl_down(v,  2, 64);
    v += __shfl_down(v,  1, 64);
    __shared__ float wsum[2];
    if ((tid & 63) == 0) wsum[tid >> 6] = v;
    __syncthreads();
    if (tid == 0) {
        float dval = fmaxf((wsum[0] + wsum[1]) * (1.0f / 96.0f), 1e-6f);
        // diagonal of full_covar, incl. the final +1e-6*eye
        out[COV_OFF + ((size_t)b * NN + i) * NN + i] = dval + 1e-6f;
    }
}

// One block per (b,i); thread j handles pair (i,j). Off-diagonal covar.
__global__ __launch_bounds__(256) void relu_cov_pair(
    const float* __restrict__ meanin, const float* __restrict__ kin,
    float* __restrict__ out)
{
    const int row = blockIdx.x;          // b*NN + i
    const int b   = row >> 8;
    const int i   = row & (NN - 1);
    const int j   = threadIdx.x;

    __shared__ __align__(16) float smi[CC];
    __shared__ __align__(16) float sEhi[CC];
    const float* __restrict__ Eh = out + EH_OFF;

    if (j < CC) {
        smi[j]  = meanin[(size_t)row * CC + j];
        sEhi[j] = Eh[(size_t)row * CC + j];
    }
    __syncthreads();

    if (j == i) return;                  // diagonal written by relu_cov_row

    const float* kb = kin + (size_t)b * NN * NN;
    const float m00 = kb[i * NN + i] + 1e-6f;
    const float m11 = kb[j * NN + j] + 1e-6f;
    const float m01 = kb[i * NN + j];    // off-diagonal: no eye term
    const float m10 = kb[j * NN + i];

    const float det = m00 * m11 - m01 * m10;
    const float s   = sqrtf(fmaxf(det, 1e-8f));
    const float t   = fmaxf(sqrtf(m00 + m11 + 2.0f * s), 1e-8f);
    const float rt  = __builtin_amdgcn_rcpf(t);
    const float s00 = (m00 + s) * rt;
    const float s01 = m01 * rt;
    const float s10 = m10 * rt;
    const float s11 = (m11 + s) * rt;
    const float dS  = fmaxf(s00 * s11 - s01 * s10, 1e-8f);
    const float rdS = __builtin_amdgcn_rcpf(dS);
    const float i00 = s11 * rdS, i01 = -s01 * rdS;
    const float i10 = -s10 * rdS, i11 = s00 * rdS;
    const float c0001   = s00 * s01;
    const float c0101_2 = 2.0f * s01 * s01;
    const float c0111   = s01 * s11;

    const float4* __restrict__ mjp  =
        reinterpret_cast<const float4*>(meanin + (size_t)(b * NN + j) * CC);
    const float4* __restrict__ Ehjp =
        reinterpret_cast<const float4*>(Eh + (size_t)(b * NN + j) * CC);
    const float4* mip  = reinterpret_cast<const float4*>(smi);
    const float4* Ehip = reinterpret_cast<const float4*>(sEhi);

    auto elem = [&](float mi, float mj, float Ehi, float Ehj) -> float {
        float u1 = i00 * mi + i01 * mj;
        float u2 = i10 * mi + i11 * mj;
        float e1 = __expf(-0.5f * u1 * u1);
        float e2 = __expf(-0.5f * u2 * u2);
        float p1 = INV_SQRT_2PI * e1;        // phi(u1)
        float p2 = INV_SQRT_2PI * e2;        // phi(u2)
        float Phi1 = phi_cdf_from_exp(u1, e1);
        float Phi2 = phi_cdf_from_exp(u2, e2);
        float r  = (mi * mj + m01) * (Phi1 * Phi2);      // EhhT_Psi
        r += (mj * s00 + mi * s10) * (p1 * Phi2);        // EhhT_psi1
        r += (mj * s01 + mi * s11) * (Phi1 * p2);        // EhhT_psi2
        r -= c0001 * (u1 * p1) * Phi2;                   // SHPhiS11 (phip = -u*phi)
        r += c0101_2 * (p1 * p2);                        // 2*SHPhiS12
        r -= c0111 * Phi1 * (u2 * p2);                   // SHPhiS22
        return r - Ehi * Ehj;
    };

    float acc = 0.0f;
#pragma unroll 2
    for (int kq = 0; kq < CC / 4; ++kq) {
        float4 mj4  = mjp[kq];
        float4 Ehj4 = Ehjp[kq];
        float4 mi4  = mip[kq];
        float4 Ehi4 = Ehip[kq];
        acc += elem(mi4.x, mj4.x, Ehi4.x, Ehj4.x);
        acc += elem(mi4.y, mj4.y, Ehi4.y, Ehj4.y);
        acc += elem(mi4.z, mj4.z, Ehi4.z, Ehj4.z);
        acc += elem(mi4.w, mj4.w, Ehi4.w, Ehj4.w);
    }

    out[COV_OFF + (size_t)row * NN + j] = acc * (1.0f / 96.0f);
}

extern "C" void kernel_launch(void* const* d_in, const int* in_sizes, int n_in,
                              void* d_out, int out_size, void* d_ws, size_t ws_size,
                              hipStream_t stream) {
    const float* xin    = (const float*)d_in[0];
    const float* meanin = (const float*)d_in[1];
    const float* kin    = (const float*)d_in[2];
    float* out = (float*)d_out;

    relu_cov_row<<<BSZ * NN, 128, 0, stream>>>(xin, meanin, kin, out);
    relu_cov_pair<<<BSZ * NN, 256, 0, stream>>>(meanin, kin, out);
}

// Round 2
// 88.951 us; speedup vs baseline: 1.1815x; 1.1815x over previous
//
#include <hip/hip_runtime.h>
#include <math.h>

#define BSZ 4
#define NN  256
#define CC  96

#define XIN_OFF  0
#define EH_OFF   2048          // BSZ*NN*2
#define COV_OFF  100352        // 2048 + BSZ*NN*CC

#define INV_SQRT_2PI 0.3989422804014327f
#define INV_SQRT2    0.7071067811865476f
#define EXP2C       -0.7213475204444817f   // -0.5*log2(e)

// Phi(u) = 0.5*(1+erf(u/sqrt2)) via Abramowitz-Stegun 7.1.26, reusing
// e = exp(-u*u/2). The 0.5 factor is folded into the coefficients.
__device__ __forceinline__ float phi_cdf_from_exp(float u, float e) {
    float x = fabsf(u) * INV_SQRT2;
    float t = __builtin_amdgcn_rcpf(__builtin_fmaf(0.3275911f, x, 1.0f));
    float poly = __builtin_fmaf(__builtin_fmaf(__builtin_fmaf(__builtin_fmaf(
                     0.5307027145f, t, -0.7265760135f), t, 0.7107068705f), t,
                     -0.142248368f), t, 0.127414796f) * t;
    float hp = poly * e;                 // = Phi(-|u|)
    return (u >= 0.0f) ? 1.0f - hp : hp;
}

// One block per (b,i) row: Eh row, dvals -> diagonal of covar, xin copy.
__global__ __launch_bounds__(128) void relu_cov_row(
    const float* __restrict__ xin, const float* __restrict__ meanin,
    const float* __restrict__ kin, float* __restrict__ out)
{
    const int row = blockIdx.x;          // b*NN + i
    const int b   = row >> 8;
    const int i   = row & (NN - 1);
    const int tid = threadIdx.x;

    const float kd   = kin[((size_t)b * NN + i) * NN + i] + 1e-6f;
    const float var  = fmaxf(kd, 1e-8f);
    const float stdv = __builtin_amdgcn_sqrtf(var);
    const float rstd = __builtin_amdgcn_rcpf(stdv);

    float dterm = 0.0f;
    if (tid < CC) {
        float m  = meanin[(size_t)row * CC + tid];
        float z  = m * rstd;
        float e  = __builtin_amdgcn_exp2f(z * z * EXP2C);
        float ph = INV_SQRT_2PI * e;         // phi(z)
        float Ph = phi_cdf_from_exp(z, e);   // Phi(z)
        float Eh = m * Ph + stdv * ph;
        out[EH_OFF + (size_t)row * CC + tid] = Eh;
        dterm = (m * m + var) * Ph + m * stdv * ph - Eh * Eh;
    } else if (tid < CC + 2) {
        int dd = tid - CC;                   // xin copy (d=2)
        out[XIN_OFF + (size_t)row * 2 + dd] = xin[(size_t)row * 2 + dd];
    }

    float v = dterm;
    v += __shfl_down(v, 32, 64);
    v += __shfl_down(v, 16, 64);
    v += __shfl_down(v,  8, 64);
    v += __shfl_down(v,  4, 64);
    v += __shfl_down(v,  2, 64);
    v += __shfl_down(v,  1, 64);
    __shared__ float wsum[2];
    if ((tid & 63) == 0) wsum[tid >> 6] = v;
    __syncthreads();
    if (tid == 0) {
        float dval = fmaxf((wsum[0] + wsum[1]) * (1.0f / 96.0f), 1e-6f);
        out[COV_OFF + ((size_t)b * NN + i) * NN + i] = dval + 1e-6f;
    }
}

// Upper-triangle pair kernel. Block = (b, i2): handles the 255 pairs of the
// balanced row-pair {i2, 255-i2}. 1024 threads: tid = (chunk<<8)|p, pair p
// owns c-range [chunk*24, chunk*24+24). LDS reduce over the 4 chunks, then
// mirrored store covar[i,j] / covar[j,i] (kin symmetric => covar symmetric).
__global__ __launch_bounds__(1024, 8) void relu_cov_pair(
    const float* __restrict__ meanin, const float* __restrict__ kin,
    float* __restrict__ out)
{
    const int blk = blockIdx.x;     // b*128 + i2
    const int b   = blk >> 7;
    const int i2  = blk & 127;
    const int tid = threadIdx.x;
    const int p   = tid & 255;
    const int ch  = tid >> 8;       // c-chunk 0..3

    __shared__ __align__(16) float smA[CC], sEA[CC], smB[CC], sEB[CC];
    __shared__ float red[1024];

    const float* __restrict__ Eh = out + EH_OFF;
    const int rowA = i2;
    const int rowB = 255 - i2;

    if (tid < CC) {
        smA[tid] = meanin[((size_t)b * NN + rowA) * CC + tid];
        sEA[tid] = Eh[((size_t)b * NN + rowA) * CC + tid];
    } else if (tid >= 128 && tid < 128 + CC) {
        int c = tid - 128;
        smB[c] = meanin[((size_t)b * NN + rowB) * CC + c];
        sEB[c] = Eh[((size_t)b * NN + rowB) * CC + c];
    }
    __syncthreads();

    const int  nfirst   = 255 - i2;
    const bool firstSeg = p < nfirst;
    const bool active   = p < 255;
    const int  i = firstSeg ? rowA : rowB;
    const int  j = firstSeg ? (i2 + 1 + p) : (p + 1);

    float acc = 0.0f;
    int iw = i, jw = j;             // for the final store
    if (active) {
        const float* kb = kin + (size_t)b * NN * NN;
        const float m00 = kb[i * NN + i] + 1e-6f;
        const float m11 = kb[j * NN + j] + 1e-6f;
        const float m01 = 0.5f * (kb[i * NN + j] + kb[j * NN + i]);

        const float det = __builtin_fmaf(-m01, m01, m00 * m11);
        const float s   = __builtin_amdgcn_sqrtf(fmaxf(det, 1e-8f));
        const float t   = fmaxf(__builtin_amdgcn_sqrtf(m00 + m11 + 2.0f * s), 1e-8f);
        const float rt  = __builtin_amdgcn_rcpf(t);
        const float s00 = (m00 + s) * rt;
        const float s01 = m01 * rt;
        const float s11 = (m11 + s) * rt;
        const float dS  = fmaxf(__builtin_fmaf(-s01, s01, s00 * s11), 1e-8f);
        const float rdS = __builtin_amdgcn_rcpf(dS);
        const float i00 = s11 * rdS;
        const float i01 = -s01 * rdS;
        const float i11 = s00 * rdS;
        const float c0001   = s00 * s01;
        const float c0101_2 = 2.0f * s01 * s01;
        const float c0111   = s01 * s11;

        const float4* mjp = (const float4*)(meanin + ((size_t)b * NN + j) * CC + ch * 24);
        const float4* Ejp = (const float4*)(Eh     + ((size_t)b * NN + j) * CC + ch * 24);
        const float4* mip = (const float4*)((firstSeg ? smA : smB) + ch * 24);
        const float4* Eip = (const float4*)((firstSeg ? sEA : sEB) + ch * 24);

        auto elem = [&](float mi, float mj, float Ehi, float Ehj) {
            float u1 = __builtin_fmaf(i01, mj, i00 * mi);
            float u2 = __builtin_fmaf(i11, mj, i01 * mi);
            float e1 = __builtin_amdgcn_exp2f(u1 * u1 * EXP2C);
            float e2 = __builtin_amdgcn_exp2f(u2 * u2 * EXP2C);
            float p1 = INV_SQRT_2PI * e1;
            float p2 = INV_SQRT_2PI * e2;
            float Phi1 = phi_cdf_from_exp(u1, e1);
            float Phi2 = phi_cdf_from_exp(u2, e2);
            // g1 = (mi*mj+m01)*Phi1 + (mj*s00 + mi*s01 - c0001*u1)*p1
            float a  = __builtin_fmaf(mi, mj, m01);
            float bb = __builtin_fmaf(mi, s01, mj * s00);
            bb = __builtin_fmaf(-c0001, u1, bb);
            float g1 = __builtin_fmaf(bb, p1, a * Phi1);
            // g2 = (mj*s01 + mi*s11 - c0111*u2)*p2
            float cc = __builtin_fmaf(mi, s11, mj * s01);
            cc = __builtin_fmaf(-c0111, u2, cc);
            float g2 = cc * p2;
            acc = __builtin_fmaf(Phi2, g1, acc);
            acc = __builtin_fmaf(Phi1, g2, acc);
            acc = __builtin_fmaf(c0101_2, p1 * p2, acc);
            acc = __builtin_fmaf(-Ehi, Ehj, acc);
        };

#pragma unroll 2
        for (int q = 0; q < 6; ++q) {
            float4 mj4 = mjp[q];
            float4 Ej4 = Ejp[q];
            float4 mi4 = mip[q];
            float4 Ei4 = Eip[q];
            elem(mi4.x, mj4.x, Ei4.x, Ej4.x);
            elem(mi4.y, mj4.y, Ei4.y, Ej4.y);
            elem(mi4.z, mj4.z, Ei4.z, Ej4.z);
            elem(mi4.w, mj4.w, Ei4.w, Ej4.w);
        }
    }

    red[tid] = acc;
    __syncthreads();

    if (tid < 256 && active) {
        float v = red[tid] + red[tid + 256] + red[tid + 512] + red[tid + 768];
        v *= (1.0f / 96.0f);
        out[COV_OFF + (((size_t)b * NN + iw) * NN + jw)] = v;
        out[COV_OFF + (((size_t)b * NN + jw) * NN + iw)] = v;
    }
}

extern "C" void kernel_launch(void* const* d_in, const int* in_sizes, int n_in,
                              void* d_out, int out_size, void* d_ws, size_t ws_size,
                              hipStream_t stream) {
    const float* xin    = (const float*)d_in[0];
    const float* meanin = (const float*)d_in[1];
    const float* kin    = (const float*)d_in[2];
    float* out = (float*)d_out;

    relu_cov_row<<<BSZ * NN, 128, 0, stream>>>(xin, meanin, kin, out);
    relu_cov_pair<<<BSZ * 128, 1024, 0, stream>>>(meanin, kin, out);
}